// Round 6
// baseline (222.536 us; speedup 1.0000x reference)
//
#include <hip/hip_runtime.h>

constexpr int SEQ = 2048;
constexpr int DM = 1024;
constexpr int NH = 16;
constexpr int BATCH = 2;
constexpr int MTOT = BATCH * SEQ;   // 4096

typedef __bf16 bf16x8 __attribute__((ext_vector_type(8)));
typedef __bf16 bf16x4 __attribute__((ext_vector_type(4)));
typedef float f32x4 __attribute__((ext_vector_type(4)));

#define MFMA16(a, b, c) __builtin_amdgcn_mfma_f32_16x16x32_bf16((a), (b), (c), 0, 0, 0)

__device__ __forceinline__ void async_copy16(const void* g, void* l) {
  __builtin_amdgcn_global_load_lds((const __attribute__((address_space(1))) void*)g,
                                   (__attribute__((address_space(3))) void*)l, 16, 0, 0);
}

__global__ void sentinel_fill(float* out, int n) {
  int i = blockIdx.x * blockDim.x + threadIdx.x;
  for (; i < n; i += gridDim.x * blockDim.x) out[i] = 0.25f;
}

// one-shot fp32 -> bf16 conversion of x, w_qkv, w_o
__global__ __launch_bounds__(256) void cvt_all(const float* __restrict__ x,
                                               const float* __restrict__ wq,
                                               const float* __restrict__ wo,
                                               __bf16* __restrict__ xb,
                                               __bf16* __restrict__ wqb,
                                               __bf16* __restrict__ wob) {
  const long i = (long)(blockIdx.x * 256 + threadIdx.x) * 8;
  const float* src;
  __bf16* dst;
  long off;
  if (i < 4194304) { src = x; dst = xb; off = i; }
  else if (i < 7340032) { src = wq; dst = wqb; off = i - 4194304; }
  else { src = wo; dst = wob; off = i - 7340032; }
  f32x4 lo = *(const f32x4*)(src + off);
  f32x4 hi = *(const f32x4*)(src + off + 4);
  bf16x8 r;
#pragma unroll
  for (int j = 0; j < 4; ++j) { r[j] = (__bf16)lo[j]; r[4 + j] = (__bf16)hi[j]; }
  *(bf16x8*)(dst + off) = r;
}

// FAST GEMM: C[M,N]=A[M,K]*B[N,K]^T, bf16 in, m97 tile geometry.
// R6: 2-PHASE double-buffered pipeline (catalog T3-minimum): issue tile t+1's
// global_load_lds FIRST, then ds_read+MFMA tile t, then vmcnt(0)+barrier.
// Load latency hides under compute (was fully exposed: stage->drain->compute).
// Race-audit: buf^1 last read before previous barrier; vmcnt(0) before the
// end-of-iter barrier guarantees staging visibility. LDS 32 KB.
template <typename OutT>
__global__ __launch_bounds__(256) void gemm_bt(const __bf16* __restrict__ A,
                                               const __bf16* __restrict__ B,
                                               OutT* __restrict__ C,
                                               int M, int N, int K, int lda,
                                               float nanSig) {
  __shared__ alignas(16) __bf16 As[2][128 * 32];
  __shared__ alignas(16) __bf16 Bs[2][128 * 32];
  const int tid = threadIdx.x;
  const int lane = tid & 63;
  const int wave = tid >> 6;
  const int lr = lane & 15;
  const int quad = lane >> 4;
  const int wm = (wave >> 1) * 64;
  const int wn = (wave & 1) * 64;
  const int m0 = blockIdx.y * 128;
  const int n0 = blockIdx.x * 128;

  const int ra = tid >> 2;
  const int ca = (tid & 3) * 8;
  const __bf16* gA0 = A + (long)(m0 + ra) * lda + ca;
  const __bf16* gA1 = A + (long)(m0 + 64 + ra) * lda + ca;
  const __bf16* gB0 = B + (long)(n0 + ra) * K + ca;
  const __bf16* gB1 = B + (long)(n0 + 64 + ra) * K + ca;

  f32x4 acc[4][4];
#pragma unroll
  for (int i = 0; i < 4; ++i)
#pragma unroll
    for (int j = 0; j < 4; ++j) acc[i][j] = (f32x4){0.f, 0.f, 0.f, 0.f};

  auto stage = [&](int bi, int k0) {
    async_copy16(gA0 + k0, &As[bi][wave * 512]);
    async_copy16(gA1 + k0, &As[bi][2048 + wave * 512]);
    async_copy16(gB0 + k0, &Bs[bi][wave * 512]);
    async_copy16(gB1 + k0, &Bs[bi][2048 + wave * 512]);
  };

  // prologue: stage tile 0, drain, barrier
  stage(0, 0);
  __builtin_amdgcn_s_waitcnt(0);
  __syncthreads();

  int cur = 0;
  for (int k0 = 0; k0 < K; k0 += 32) {
    if (k0 + 32 < K) stage(cur ^ 1, k0 + 32);  // next tile in flight
    bf16x8 af[4], bfr[4];
#pragma unroll
    for (int i = 0; i < 4; ++i)
      af[i] = *(const bf16x8*)&As[cur][(wm + i * 16 + lr) * 32 + quad * 8];
#pragma unroll
    for (int j = 0; j < 4; ++j)
      bfr[j] = *(const bf16x8*)&Bs[cur][(wn + j * 16 + lr) * 32 + quad * 8];
    __builtin_amdgcn_s_setprio(1);
#pragma unroll
    for (int i = 0; i < 4; ++i)
#pragma unroll
      for (int j = 0; j < 4; ++j) acc[i][j] = MFMA16(af[i], bfr[j], acc[i][j]);
    __builtin_amdgcn_s_setprio(0);
    __builtin_amdgcn_s_waitcnt(0);  // staging of buf^1 complete
    __syncthreads();                // all waves done reading buf[cur]
    cur ^= 1;
  }

#pragma unroll
  for (int i = 0; i < 4; ++i) {
    const int row = m0 + wm + i * 16 + quad * 4;
#pragma unroll
    for (int j = 0; j < 4; ++j) {
      const int col = n0 + wn + j * 16 + lr;
#pragma unroll
      for (int r = 0; r < 4; ++r) {
        float v = acc[i][j][r];
        if (!(v == v)) v = nanSig;
        C[(long)(row + r) * N + col] = (OutT)v;
      }
    }
  }
}

// SLOW fallback GEMM (inline fp32 cvt, verified R9).
template <int F32>
__device__ __forceinline__ bf16x8 load_cvt8(const void* base, long off) {
  if constexpr (F32) {
    const float* p = (const float*)base + off;
    f32x4 lo = *(const f32x4*)p;
    f32x4 hi = *(const f32x4*)(p + 4);
    bf16x8 r;
#pragma unroll
    for (int j = 0; j < 4; ++j) { r[j] = (__bf16)lo[j]; r[4 + j] = (__bf16)hi[j]; }
    return r;
  } else {
    return *(const bf16x8*)((const __bf16*)base + off);
  }
}

template <int AF32, int BF32, typename OutT>
__global__ __launch_bounds__(256) void gemm_nt(const void* __restrict__ Av,
                                               const void* __restrict__ Bv,
                                               OutT* __restrict__ C,
                                               int M, int N, int K, int lda,
                                               float nanSig) {
  __shared__ alignas(16) __bf16 As[128 * 32];
  __shared__ alignas(16) __bf16 Bs[128 * 32];
  const int tid = threadIdx.x;
  const int lane = tid & 63;
  const int wave = tid >> 6;
  const int lr = lane & 15;
  const int quad = lane >> 4;
  const int wm = (wave >> 1) * 64;
  const int wn = (wave & 1) * 64;
  const int m0 = blockIdx.y * 128;
  const int n0 = blockIdx.x * 128;

  const int r0 = tid >> 2;
  const int r1 = 64 + (tid >> 2);
  const int cc = (tid & 3) * 8;
  const long aBase0 = (long)(m0 + r0) * lda + cc;
  const long aBase1 = (long)(m0 + r1) * lda + cc;
  const long bBase0 = (long)(n0 + r0) * K + cc;
  const long bBase1 = (long)(n0 + r1) * K + cc;
  __bf16* lA0 = &As[r0 * 32 + cc];
  __bf16* lA1 = &As[r1 * 32 + cc];
  __bf16* lB0 = &Bs[r0 * 32 + cc];
  __bf16* lB1 = &Bs[r1 * 32 + cc];

  f32x4 acc[4][4];
#pragma unroll
  for (int i = 0; i < 4; ++i)
#pragma unroll
    for (int j = 0; j < 4; ++j) acc[i][j] = (f32x4){0.f, 0.f, 0.f, 0.f};

  for (int k0 = 0; k0 < K; k0 += 32) {
    bf16x8 va0 = load_cvt8<AF32>(Av, aBase0 + k0);
    bf16x8 va1 = load_cvt8<AF32>(Av, aBase1 + k0);
    bf16x8 vb0 = load_cvt8<BF32>(Bv, bBase0 + k0);
    bf16x8 vb1 = load_cvt8<BF32>(Bv, bBase1 + k0);
    __syncthreads();
    *(bf16x8*)lA0 = va0;
    *(bf16x8*)lA1 = va1;
    *(bf16x8*)lB0 = vb0;
    *(bf16x8*)lB1 = vb1;
    __syncthreads();
    bf16x8 af[4], bfr[4];
#pragma unroll
    for (int i = 0; i < 4; ++i) af[i] = *(const bf16x8*)&As[(wm + i * 16 + lr) * 32 + quad * 8];
#pragma unroll
    for (int j = 0; j < 4; ++j) bfr[j] = *(const bf16x8*)&Bs[(wn + j * 16 + lr) * 32 + quad * 8];
#pragma unroll
    for (int i = 0; i < 4; ++i)
#pragma unroll
      for (int j = 0; j < 4; ++j) acc[i][j] = MFMA16(af[i], bfr[j], acc[i][j]);
  }

#pragma unroll
  for (int i = 0; i < 4; ++i) {
    const int row = m0 + wm + i * 16 + quad * 4;
#pragma unroll
    for (int j = 0; j < 4; ++j) {
      const int col = n0 + wn + j * 16 + lr;
#pragma unroll
      for (int r = 0; r < 4; ++r) {
        float v = acc[i][j][r];
        if (!(v == v)) v = nanSig;
        C[(long)(row + r) * N + col] = (OutT)v;
      }
    }
  }
}

// Flash causal attention, S^T form. R5 FAT BLOCKS (kept): 512 threads = 8
// waves, block owns pairs (2j, 2j+1); waves 0-3 pair 2j, waves 4-7 pair 2j+1.
// Grid 8x16x2 = 256 blocks = 1/CU. LDS dbuf Ks/Vt, single barrier per tile,
// shared-av PV, T13 defer-rescale, T5 setprio, LDS-only P fence. 79us steady.
// Vt is XOR-swizzled (kv ^= 8*((d>>3)&3)) to kill the 8-way write conflict.
__global__ __launch_bounds__(512, 2) void attn_fwd(__bf16* __restrict__ qkv) {
  const int jj = blockIdx.x;      // 0..7: pair group
  const int h = blockIdx.y;
  const int b = blockIdx.z;
  const int tid = threadIdx.x;
  const int lane = tid & 63;
  const int wave = tid >> 6;      // 0..7
  const int ps = wave >> 2;       // 0: pair 2j, 1: pair 2j+1
  const int pi = 2 * jj + ps;     // 0..15
  const int q0A = pi * 64;
  const int q0B = (31 - pi) * 64;
  const int lr = lane & 15;
  const int quad = lane >> 4;
  const int wq = (wave & 3) * 16;

  __shared__ alignas(16) __bf16 Ks[2][64 * 72];  // K rows [kv][d], double-buffered
  __shared__ alignas(16) __bf16 Vt[2][64 * 72];  // V^T [d][kv^swz], double-buffered
  __shared__ alignas(16) __bf16 Pq[256 * 72];    // P [wave*32 + qg*16 + q][kv]

  __bf16* pqw = &Pq[wave * 32 * 72];
  const long base = (long)b * SEQ * 3072;
  const int qi[2] = {q0A + wq + lr, q0B + wq + lr};

  // Q as B-operand fragments (loaded once)
  bf16x8 b_q[2][2];
#pragma unroll
  for (int qg = 0; qg < 2; ++qg) {
    const long rowoff = base + (long)qi[qg] * 3072 + h * 64;
    b_q[qg][0] = *(const bf16x8*)(qkv + rowoff + quad * 8);
    b_q[qg][1] = *(const bf16x8*)(qkv + rowoff + 32 + quad * 8);
  }

  const float NEGS = -30000.f;
  const float SC = 0.18033688f;  // 0.125 * log2(e): softmax in exp2 domain
  float m_i[2] = {NEGS, NEGS}, l_i[2] = {0.f, 0.f};
  f32x4 o_acc[2][4];
#pragma unroll
  for (int qg = 0; qg < 2; ++qg)
#pragma unroll
    for (int dt = 0; dt < 4; ++dt) o_acc[qg][dt] = (f32x4){0.f, 0.f, 0.f, 0.f};

  // staging thread geometry (512 stagers: 1 row each)
  const int r_ = tid >> 3;            // 0..63
  const int col_ = (tid & 7) * 8;     // 0..56
  const int l8 = tid & 7;
  const int sw = (l8 & 3) << 3;       // Vt swizzle amount for this thread's cols
  const bool oddr = (tid >> 3) & 1;
  const int jb = oddr ? 4 : 0;

  const int Tb = 32 - 2 * jj;         // staged tiles (pair 2j's range), >= 18
  const int Tp = 32 - pi;             // this wave's pair compute range (Tb or Tb-1)

  bf16x8 kreg, vreg;
  auto loadTile = [&](int t) {
    const long ro = base + ((long)t * 64 + r_) * 3072 + h * 64 + col_;
    kreg = *(const bf16x8*)(qkv + ro + 1024);
    vreg = *(const bf16x8*)(qkv + ro + 2048);
  };
  auto stageTile = [&](int bi) {
    __bf16* ks = &Ks[bi][0];
    __bf16* vt = &Vt[bi][0];
    // K row -> LDS (b128)
    *(bf16x8*)&ks[r_ * 72 + col_] = kreg;
    // V^T via pair-transpose + swizzle (b32 writes, 2-way banks = free)
    const int rr = (r_ & ~1) ^ sw;
    int vd[4], od[4];
    __builtin_memcpy(vd, &vreg, 16);
#pragma unroll
    for (int i = 0; i < 4; ++i) od[i] = __shfl_xor(vd[i], 8);
#pragma unroll
    for (int i = 0; i < 4; ++i) {
      const int j = jb + i;
      const int a = vd[j >> 1], bb = od[j >> 1];
      const int lo = oddr ? bb : a;
      const int hi = oddr ? a : bb;
      const int pair = (j & 1) ? (int)(((unsigned)lo >> 16) | (hi & 0xffff0000))
                               : (int)((lo & 0xffff) | (hi << 16));
      *(int*)&vt[(col_ + j) * 72 + rr] = pair;
    }
  };

  // prologue: stage tile 0 into buf0, issue loads for tile 1
  loadTile(0);
  stageTile(0);
  loadTile(1);  // Tb >= 18, always valid
  __syncthreads();

  for (int t = 0; t < Tb; ++t) {
    const int cur = t & 1;
    const int kv0 = t * 64;
    const bool active = (t < Tp);              // wave-uniform
    const bool actA = (kv0 <= q0A + wq + 15);  // wave-uniform

    // S^T = K * Q^T (K-frags shared across both q-groups) from Ks[cur]
    f32x4 st[2][4];
#pragma unroll
    for (int kt = 0; kt < 4; ++kt) {
      st[1][kt] = (f32x4){0.f, 0.f, 0.f, 0.f};
      st[0][kt] = (f32x4){0.f, 0.f, 0.f, 0.f};
    }
    if (active) {
      __builtin_amdgcn_s_setprio(1);
#pragma unroll
      for (int ks = 0; ks < 2; ++ks) {
        bf16x8 ak[4];
#pragma unroll
        for (int kt = 0; kt < 4; ++kt)
          ak[kt] = *(const bf16x8*)&Ks[cur][(kt * 16 + lr) * 72 + ks * 32 + quad * 8];
#pragma unroll
        for (int kt = 0; kt < 4; ++kt) st[1][kt] = MFMA16(ak[kt], b_q[1][ks], st[1][kt]);
        if (actA) {
#pragma unroll
          for (int kt = 0; kt < 4; ++kt) st[0][kt] = MFMA16(ak[kt], b_q[0][ks], st[0][kt]);
        }
      }
      __builtin_amdgcn_s_setprio(0);
    }

    // stage tile t+1 into the other buffer (overlaps with softmax below),
    // then issue global loads for tile t+2 (consumed by next iter's stage).
    if (t + 1 < Tb) stageTile(cur ^ 1);
    if (t + 2 < Tb) loadTile(t + 2);

    if (active) {
      // softmax for BOTH q-groups (independent chains -> ILP), P -> LDS
#pragma unroll
      for (int qg = 1; qg >= 0; --qg) {
        if (qg == 0 && !actA) continue;
        const int q0X = (qg == 0) ? q0A : q0B;
        // scale (exp2 domain) + causal mask
        if (kv0 + 64 <= q0X + wq) {
#pragma unroll
          for (int kt = 0; kt < 4; ++kt)
#pragma unroll
            for (int r = 0; r < 4; ++r) st[qg][kt][r] *= SC;
        } else {
#pragma unroll
          for (int kt = 0; kt < 4; ++kt) {
            const int d0 = kv0 + kt * 16 + quad * 4 - qi[qg];
#pragma unroll
            for (int r = 0; r < 4; ++r)
              st[qg][kt][r] = (d0 + r <= 0) ? st[qg][kt][r] * SC : NEGS;
          }
        }
        // online softmax (in-lane over 16 kv + 2 shfl)
        float mx = st[qg][0][0];
#pragma unroll
        for (int kt = 0; kt < 4; ++kt)
#pragma unroll
          for (int r = 0; r < 4; ++r) mx = fmaxf(mx, st[qg][kt][r]);
        mx = fmaxf(mx, __shfl_xor(mx, 16));
        mx = fmaxf(mx, __shfl_xor(mx, 32));
        // T13 defer-rescale: keep old max while growth <= 8 (P bounded by 2^8)
        const bool noresc = __all(mx - m_i[qg] <= 8.f);
        const float mnew = noresc ? m_i[qg] : fmaxf(m_i[qg], mx);
        float rs = 0.f;
#pragma unroll
        for (int kt = 0; kt < 4; ++kt)
#pragma unroll
          for (int r = 0; r < 4; ++r) {
            const float p = exp2f(st[qg][kt][r] - mnew);
            st[qg][kt][r] = p;
            rs += p;
          }
        rs += __shfl_xor(rs, 16);
        rs += __shfl_xor(rs, 32);
        // P -> wave-private LDS (b64 writes, 2-way = free)
#pragma unroll
        for (int kt = 0; kt < 4; ++kt) {
          bf16x4 pv;
#pragma unroll
          for (int r = 0; r < 4; ++r) pv[r] = (__bf16)st[qg][kt][r];
          *(bf16x4*)&pqw[(qg * 16 + lr) * 72 + kt * 16 + quad * 4] = pv;
        }
        if (noresc) {
          l_i[qg] += rs;
        } else {
          const float alpha = exp2f(m_i[qg] - mnew);
          l_i[qg] = l_i[qg] * alpha + rs;
          m_i[qg] = mnew;
#pragma unroll
          for (int dt = 0; dt < 4; ++dt)
#pragma unroll
            for (int r = 0; r < 4; ++r) o_acc[qg][dt][r] *= alpha;
        }
      }

      // single LDS-only fence: P writes visible to own wave's ds_reads;
      // leaves the depth-2 global prefetch in flight.
      asm volatile("s_waitcnt lgkmcnt(0)" ::: "memory");
      __builtin_amdgcn_sched_barrier(0);

      // O^T += V^T * P^T; av (V^T) fragments shared by both q-groups
      __builtin_amdgcn_s_setprio(1);
#pragma unroll
      for (int ks = 0; ks < 2; ++ks) {
        bf16x8 av[4];
#pragma unroll
        for (int dt = 0; dt < 4; ++dt) {
          const int blk = ((ks << 2) + quad) ^ ((2 * dt + (lr >> 3)) & 3);
          av[dt] = *(const bf16x8*)&Vt[cur][(dt * 16 + lr) * 72 + (blk << 3)];
        }
        {
          bf16x8 bp = *(const bf16x8*)&pqw[(16 + lr) * 72 + ks * 32 + quad * 8];
#pragma unroll
          for (int dt = 0; dt < 4; ++dt) o_acc[1][dt] = MFMA16(av[dt], bp, o_acc[1][dt]);
        }
        if (actA) {
          bf16x8 bp = *(const bf16x8*)&pqw[lr * 72 + ks * 32 + quad * 8];
#pragma unroll
          for (int dt = 0; dt < 4; ++dt) o_acc[0][dt] = MFMA16(av[dt], bp, o_acc[0][dt]);
        }
      }
      __builtin_amdgcn_s_setprio(0);
    }

    __syncthreads();  // single barrier per tile: staging of t+1 visible,
                      // reads of buf[cur] complete before iter t+1 overwrites
  }

  // epilogue: O/l -> q-slice in place
#pragma unroll
  for (int qg = 0; qg < 2; ++qg) {
    const float inv = 1.f / fmaxf(l_i[qg], 1e-30f);
    const long obase = base + (long)qi[qg] * 3072 + h * 64 + quad * 4;
#pragma unroll
    for (int dt = 0; dt < 4; ++dt) {
      bf16x4 ov;
#pragma unroll
      for (int r = 0; r < 4; ++r) ov[r] = (__bf16)(o_acc[qg][dt][r] * inv);
      *(bf16x4*)(qkv + obase + dt * 16) = ov;
    }
  }
}

extern "C" void kernel_launch(void* const* d_in, const int* in_sizes, int n_in,
                              void* d_out, int out_size, void* d_ws, size_t ws_size,
                              hipStream_t stream) {
  const float* x = (const float*)d_in[0];
  const float* w_qkv = (const float*)d_in[1];
  const float* w_o = (const float*)d_in[2];
  for (int i = 0; i < n_in; ++i) {
    if (in_sizes[i] == MTOT * DM) x = (const float*)d_in[i];
    else if (in_sizes[i] == 3 * DM * DM) w_qkv = (const float*)d_in[i];
    else if (in_sizes[i] == DM * DM) w_o = (const float*)d_in[i];
  }
  float* out = (float*)d_out;  // FP32 output per reference dtype

  const size_t qkvBytes = (size_t)MTOT * 3072 * 2;       // 24 MiB
  const size_t xbBytes = (size_t)MTOT * DM * 2;          // 8 MiB
  const size_t wqBytes = (size_t)3 * DM * DM * 2;        // 6 MiB
  const size_t woBytes = (size_t)DM * DM * 2;            // 2 MiB
  const size_t needFast = qkvBytes + xbBytes + wqBytes + woBytes;  // 40 MiB

  __bf16* qkv = (__bf16*)d_ws;

  if (ws_size >= needFast) {
    __bf16* xb = (__bf16*)((char*)d_ws + qkvBytes);
    __bf16* wqb = (__bf16*)((char*)d_ws + qkvBytes + xbBytes);
    __bf16* wob = (__bf16*)((char*)d_ws + qkvBytes + xbBytes + wqBytes);
    cvt_all<<<4096, 256, 0, stream>>>(x, w_qkv, w_o, xb, wqb, wob);
    gemm_bt<__bf16><<<dim3(3072 / 128, MTOT / 128), 256, 0, stream>>>(
        xb, wqb, qkv, MTOT, 3072, DM, DM, 1e4f);
    attn_fwd<<<dim3(8, NH, BATCH), 512, 0, stream>>>(qkv);
    gemm_bt<float><<<dim3(DM / 128, MTOT / 128), 256, 0, stream>>>(
        qkv, wob, out, MTOT, DM, DM, 3072, 2e4f);
  } else if (ws_size >= qkvBytes) {
    gemm_nt<1, 1, __bf16><<<dim3(3072 / 128, MTOT / 128), 256, 0, stream>>>(
        x, w_qkv, qkv, MTOT, 3072, DM, DM, 1e4f);
    attn_fwd<<<dim3(8, NH, BATCH), 512, 0, stream>>>(qkv);
    gemm_nt<0, 1, float><<<dim3(DM / 128, MTOT / 128), 256, 0, stream>>>(
        qkv, w_o, out, MTOT, DM, DM, 3072, 2e4f);
  } else {
    sentinel_fill<<<256, 256, 0, stream>>>(out, out_size);
  }
}

// Round 7
// 219.085 us; speedup vs baseline: 1.0158x; 1.0158x over previous
//
#include <hip/hip_runtime.h>

constexpr int SEQ = 2048;
constexpr int DM = 1024;
constexpr int NH = 16;
constexpr int BATCH = 2;
constexpr int MTOT = BATCH * SEQ;   // 4096

typedef __bf16 bf16x8 __attribute__((ext_vector_type(8)));
typedef __bf16 bf16x4 __attribute__((ext_vector_type(4)));
typedef float f32x4 __attribute__((ext_vector_type(4)));

#define MFMA16(a, b, c) __builtin_amdgcn_mfma_f32_16x16x32_bf16((a), (b), (c), 0, 0, 0)

__device__ __forceinline__ void async_copy16(const void* g, void* l) {
  __builtin_amdgcn_global_load_lds((const __attribute__((address_space(1))) void*)g,
                                   (__attribute__((address_space(3))) void*)l, 16, 0, 0);
}

// T1 bijective XCD swizzle: each of the 8 XCDs gets a contiguous chunk of
// linear block ids -> neighboring M-panels share one XCD's L2. Requires
// nwg % 8 == 0 (both GEMM grids satisfy this: 768, 512).
__device__ __forceinline__ void xcd_swizzle(int& bx, int& by) {
  const int gx = gridDim.x;
  const int nwg = gx * gridDim.y;
  const int bid = blockIdx.y * gx + blockIdx.x;
  const int cpx = nwg >> 3;
  const int v = (bid & 7) * cpx + (bid >> 3);
  by = v / gx;
  bx = v - by * gx;
}

__global__ void sentinel_fill(float* out, int n) {
  int i = blockIdx.x * blockDim.x + threadIdx.x;
  for (; i < n; i += gridDim.x * blockDim.x) out[i] = 0.25f;
}

// one-shot fp32 -> bf16 conversion of x, w_qkv, w_o
__global__ __launch_bounds__(256) void cvt_all(const float* __restrict__ x,
                                               const float* __restrict__ wq,
                                               const float* __restrict__ wo,
                                               __bf16* __restrict__ xb,
                                               __bf16* __restrict__ wqb,
                                               __bf16* __restrict__ wob) {
  const long i = (long)(blockIdx.x * 256 + threadIdx.x) * 8;
  const float* src;
  __bf16* dst;
  long off;
  if (i < 4194304) { src = x; dst = xb; off = i; }
  else if (i < 7340032) { src = wq; dst = wqb; off = i - 4194304; }
  else { src = wo; dst = wob; off = i - 7340032; }
  f32x4 lo = *(const f32x4*)(src + off);
  f32x4 hi = *(const f32x4*)(src + off + 4);
  bf16x8 r;
#pragma unroll
  for (int j = 0; j < 4; ++j) { r[j] = (__bf16)lo[j]; r[4 + j] = (__bf16)hi[j]; }
  *(bf16x8*)(dst + off) = r;
}

// FAST GEMM: C[M,N]=A[M,K]*B[N,K]^T, bf16 in, m97 tile geometry, 128x128 tile.
// R6 2-phase double-buffer + R7 XCD swizzle (A-panels L2-resident per XCD).
template <typename OutT>
__global__ __launch_bounds__(256) void gemm_bt(const __bf16* __restrict__ A,
                                               const __bf16* __restrict__ B,
                                               OutT* __restrict__ C,
                                               int M, int N, int K, int lda,
                                               float nanSig) {
  __shared__ alignas(16) __bf16 As[2][128 * 32];
  __shared__ alignas(16) __bf16 Bs[2][128 * 32];
  const int tid = threadIdx.x;
  const int lane = tid & 63;
  const int wave = tid >> 6;
  const int lr = lane & 15;
  const int quad = lane >> 4;
  const int wm = (wave >> 1) * 64;
  const int wn = (wave & 1) * 64;
  int bx, by;
  xcd_swizzle(bx, by);
  const int m0 = by * 128;
  const int n0 = bx * 128;

  const int ra = tid >> 2;
  const int ca = (tid & 3) * 8;
  const __bf16* gA0 = A + (long)(m0 + ra) * lda + ca;
  const __bf16* gA1 = A + (long)(m0 + 64 + ra) * lda + ca;
  const __bf16* gB0 = B + (long)(n0 + ra) * K + ca;
  const __bf16* gB1 = B + (long)(n0 + 64 + ra) * K + ca;

  f32x4 acc[4][4];
#pragma unroll
  for (int i = 0; i < 4; ++i)
#pragma unroll
    for (int j = 0; j < 4; ++j) acc[i][j] = (f32x4){0.f, 0.f, 0.f, 0.f};

  auto stage = [&](int bi, int k0) {
    async_copy16(gA0 + k0, &As[bi][wave * 512]);
    async_copy16(gA1 + k0, &As[bi][2048 + wave * 512]);
    async_copy16(gB0 + k0, &Bs[bi][wave * 512]);
    async_copy16(gB1 + k0, &Bs[bi][2048 + wave * 512]);
  };

  stage(0, 0);
  __builtin_amdgcn_s_waitcnt(0);
  __syncthreads();

  int cur = 0;
  for (int k0 = 0; k0 < K; k0 += 32) {
    if (k0 + 32 < K) stage(cur ^ 1, k0 + 32);  // next tile in flight
    bf16x8 af[4], bfr[4];
#pragma unroll
    for (int i = 0; i < 4; ++i)
      af[i] = *(const bf16x8*)&As[cur][(wm + i * 16 + lr) * 32 + quad * 8];
#pragma unroll
    for (int j = 0; j < 4; ++j)
      bfr[j] = *(const bf16x8*)&Bs[cur][(wn + j * 16 + lr) * 32 + quad * 8];
    __builtin_amdgcn_s_setprio(1);
#pragma unroll
    for (int i = 0; i < 4; ++i)
#pragma unroll
      for (int j = 0; j < 4; ++j) acc[i][j] = MFMA16(af[i], bfr[j], acc[i][j]);
    __builtin_amdgcn_s_setprio(0);
    __builtin_amdgcn_s_waitcnt(0);  // staging of buf^1 complete
    __syncthreads();                // all waves done reading buf[cur]
    cur ^= 1;
  }

#pragma unroll
  for (int i = 0; i < 4; ++i) {
    const int row = m0 + wm + i * 16 + quad * 4;
#pragma unroll
    for (int j = 0; j < 4; ++j) {
      const int col = n0 + wn + j * 16 + lr;
#pragma unroll
      for (int r = 0; r < 4; ++r) {
        float v = acc[i][j][r];
        if (!(v == v)) v = nanSig;
        C[(long)(row + r) * N + col] = (OutT)v;
      }
    }
  }
}

// R7: 64x128-tile variant for gemm2 (M=4096, N=1024): grid (8,64) = 512 blocks
// = 2 blocks/CU, 2 waves/SIMD (was 256 blocks = 1 block/CU = 1 wave/SIMD ->
// zero latency hiding). Per-wave 32x64 output (acc 2x4). Same 2-phase loop.
template <typename OutT>
__global__ __launch_bounds__(256) void gemm_bt64(const __bf16* __restrict__ A,
                                                 const __bf16* __restrict__ B,
                                                 OutT* __restrict__ C,
                                                 int M, int N, int K, int lda,
                                                 float nanSig) {
  __shared__ alignas(16) __bf16 As[2][64 * 32];
  __shared__ alignas(16) __bf16 Bs[2][128 * 32];
  const int tid = threadIdx.x;
  const int lane = tid & 63;
  const int wave = tid >> 6;
  const int lr = lane & 15;
  const int quad = lane >> 4;
  const int wm = (wave >> 1) * 32;
  const int wn = (wave & 1) * 64;
  int bx, by;
  xcd_swizzle(bx, by);
  const int m0 = by * 64;
  const int n0 = bx * 128;

  const int ra = tid >> 2;          // 0..63
  const int ca = (tid & 3) * 8;
  const __bf16* gA0 = A + (long)(m0 + ra) * lda + ca;
  const __bf16* gB0 = B + (long)(n0 + ra) * K + ca;
  const __bf16* gB1 = B + (long)(n0 + 64 + ra) * K + ca;

  f32x4 acc[2][4];
#pragma unroll
  for (int i = 0; i < 2; ++i)
#pragma unroll
    for (int j = 0; j < 4; ++j) acc[i][j] = (f32x4){0.f, 0.f, 0.f, 0.f};

  auto stage = [&](int bi, int k0) {
    async_copy16(gA0 + k0, &As[bi][wave * 512]);
    async_copy16(gB0 + k0, &Bs[bi][wave * 512]);
    async_copy16(gB1 + k0, &Bs[bi][2048 + wave * 512]);
  };

  stage(0, 0);
  __builtin_amdgcn_s_waitcnt(0);
  __syncthreads();

  int cur = 0;
  for (int k0 = 0; k0 < K; k0 += 32) {
    if (k0 + 32 < K) stage(cur ^ 1, k0 + 32);
    bf16x8 af[2], bfr[4];
#pragma unroll
    for (int i = 0; i < 2; ++i)
      af[i] = *(const bf16x8*)&As[cur][(wm + i * 16 + lr) * 32 + quad * 8];
#pragma unroll
    for (int j = 0; j < 4; ++j)
      bfr[j] = *(const bf16x8*)&Bs[cur][(wn + j * 16 + lr) * 32 + quad * 8];
    __builtin_amdgcn_s_setprio(1);
#pragma unroll
    for (int i = 0; i < 2; ++i)
#pragma unroll
      for (int j = 0; j < 4; ++j) acc[i][j] = MFMA16(af[i], bfr[j], acc[i][j]);
    __builtin_amdgcn_s_setprio(0);
    __builtin_amdgcn_s_waitcnt(0);
    __syncthreads();
    cur ^= 1;
  }

#pragma unroll
  for (int i = 0; i < 2; ++i) {
    const int row = m0 + wm + i * 16 + quad * 4;
#pragma unroll
    for (int j = 0; j < 4; ++j) {
      const int col = n0 + wn + j * 16 + lr;
#pragma unroll
      for (int r = 0; r < 4; ++r) {
        float v = acc[i][j][r];
        if (!(v == v)) v = nanSig;
        C[(long)(row + r) * N + col] = (OutT)v;
      }
    }
  }
}

// SLOW fallback GEMM (inline fp32 cvt, verified R9).
template <int F32>
__device__ __forceinline__ bf16x8 load_cvt8(const void* base, long off) {
  if constexpr (F32) {
    const float* p = (const float*)base + off;
    f32x4 lo = *(const f32x4*)p;
    f32x4 hi = *(const f32x4*)(p + 4);
    bf16x8 r;
#pragma unroll
    for (int j = 0; j < 4; ++j) { r[j] = (__bf16)lo[j]; r[4 + j] = (__bf16)hi[j]; }
    return r;
  } else {
    return *(const bf16x8*)((const __bf16*)base + off);
  }
}

template <int AF32, int BF32, typename OutT>
__global__ __launch_bounds__(256) void gemm_nt(const void* __restrict__ Av,
                                               const void* __restrict__ Bv,
                                               OutT* __restrict__ C,
                                               int M, int N, int K, int lda,
                                               float nanSig) {
  __shared__ alignas(16) __bf16 As[128 * 32];
  __shared__ alignas(16) __bf16 Bs[128 * 32];
  const int tid = threadIdx.x;
  const int lane = tid & 63;
  const int wave = tid >> 6;
  const int lr = lane & 15;
  const int quad = lane >> 4;
  const int wm = (wave >> 1) * 64;
  const int wn = (wave & 1) * 64;
  const int m0 = blockIdx.y * 128;
  const int n0 = blockIdx.x * 128;

  const int r0 = tid >> 2;
  const int r1 = 64 + (tid >> 2);
  const int cc = (tid & 3) * 8;
  const long aBase0 = (long)(m0 + r0) * lda + cc;
  const long aBase1 = (long)(m0 + r1) * lda + cc;
  const long bBase0 = (long)(n0 + r0) * K + cc;
  const long bBase1 = (long)(n0 + r1) * K + cc;
  __bf16* lA0 = &As[r0 * 32 + cc];
  __bf16* lA1 = &As[r1 * 32 + cc];
  __bf16* lB0 = &Bs[r0 * 32 + cc];
  __bf16* lB1 = &Bs[r1 * 32 + cc];

  f32x4 acc[4][4];
#pragma unroll
  for (int i = 0; i < 4; ++i)
#pragma unroll
    for (int j = 0; j < 4; ++j) acc[i][j] = (f32x4){0.f, 0.f, 0.f, 0.f};

  for (int k0 = 0; k0 < K; k0 += 32) {
    bf16x8 va0 = load_cvt8<AF32>(Av, aBase0 + k0);
    bf16x8 va1 = load_cvt8<AF32>(Av, aBase1 + k0);
    bf16x8 vb0 = load_cvt8<BF32>(Bv, bBase0 + k0);
    bf16x8 vb1 = load_cvt8<BF32>(Bv, bBase1 + k0);
    __syncthreads();
    *(bf16x8*)lA0 = va0;
    *(bf16x8*)lA1 = va1;
    *(bf16x8*)lB0 = vb0;
    *(bf16x8*)lB1 = vb1;
    __syncthreads();
    bf16x8 af[4], bfr[4];
#pragma unroll
    for (int i = 0; i < 4; ++i) af[i] = *(const bf16x8*)&As[(wm + i * 16 + lr) * 32 + quad * 8];
#pragma unroll
    for (int j = 0; j < 4; ++j) bfr[j] = *(const bf16x8*)&Bs[(wn + j * 16 + lr) * 32 + quad * 8];
#pragma unroll
    for (int i = 0; i < 4; ++i)
#pragma unroll
      for (int j = 0; j < 4; ++j) acc[i][j] = MFMA16(af[i], bfr[j], acc[i][j]);
  }

#pragma unroll
  for (int i = 0; i < 4; ++i) {
    const int row = m0 + wm + i * 16 + quad * 4;
#pragma unroll
    for (int j = 0; j < 4; ++j) {
      const int col = n0 + wn + j * 16 + lr;
#pragma unroll
      for (int r = 0; r < 4; ++r) {
        float v = acc[i][j][r];
        if (!(v == v)) v = nanSig;
        C[(long)(row + r) * N + col] = (OutT)v;
      }
    }
  }
}

// Flash causal attention, S^T form. R5 FAT BLOCKS (kept, untouched): 512
// threads = 8 waves, block owns pairs (2j, 2j+1). Grid 8x16x2 = 256 blocks.
// LDS dbuf Ks/Vt, single barrier per tile, shared-av PV, T13 defer-rescale,
// T5 setprio, LDS-only P fence. 79-90us (noise band).
// Vt is XOR-swizzled (kv ^= 8*((d>>3)&3)) to kill the 8-way write conflict.
__global__ __launch_bounds__(512, 2) void attn_fwd(__bf16* __restrict__ qkv) {
  const int jj = blockIdx.x;      // 0..7: pair group
  const int h = blockIdx.y;
  const int b = blockIdx.z;
  const int tid = threadIdx.x;
  const int lane = tid & 63;
  const int wave = tid >> 6;      // 0..7
  const int ps = wave >> 2;       // 0: pair 2j, 1: pair 2j+1
  const int pi = 2 * jj + ps;     // 0..15
  const int q0A = pi * 64;
  const int q0B = (31 - pi) * 64;
  const int lr = lane & 15;
  const int quad = lane >> 4;
  const int wq = (wave & 3) * 16;

  __shared__ alignas(16) __bf16 Ks[2][64 * 72];  // K rows [kv][d], double-buffered
  __shared__ alignas(16) __bf16 Vt[2][64 * 72];  // V^T [d][kv^swz], double-buffered
  __shared__ alignas(16) __bf16 Pq[256 * 72];    // P [wave*32 + qg*16 + q][kv]

  __bf16* pqw = &Pq[wave * 32 * 72];
  const long base = (long)b * SEQ * 3072;
  const int qi[2] = {q0A + wq + lr, q0B + wq + lr};

  // Q as B-operand fragments (loaded once)
  bf16x8 b_q[2][2];
#pragma unroll
  for (int qg = 0; qg < 2; ++qg) {
    const long rowoff = base + (long)qi[qg] * 3072 + h * 64;
    b_q[qg][0] = *(const bf16x8*)(qkv + rowoff + quad * 8);
    b_q[qg][1] = *(const bf16x8*)(qkv + rowoff + 32 + quad * 8);
  }

  const float NEGS = -30000.f;
  const float SC = 0.18033688f;  // 0.125 * log2(e): softmax in exp2 domain
  float m_i[2] = {NEGS, NEGS}, l_i[2] = {0.f, 0.f};
  f32x4 o_acc[2][4];
#pragma unroll
  for (int qg = 0; qg < 2; ++qg)
#pragma unroll
    for (int dt = 0; dt < 4; ++dt) o_acc[qg][dt] = (f32x4){0.f, 0.f, 0.f, 0.f};

  // staging thread geometry (512 stagers: 1 row each)
  const int r_ = tid >> 3;            // 0..63
  const int col_ = (tid & 7) * 8;     // 0..56
  const int l8 = tid & 7;
  const int sw = (l8 & 3) << 3;       // Vt swizzle amount for this thread's cols
  const bool oddr = (tid >> 3) & 1;
  const int jb = oddr ? 4 : 0;

  const int Tb = 32 - 2 * jj;         // staged tiles (pair 2j's range), >= 18
  const int Tp = 32 - pi;             // this wave's pair compute range (Tb or Tb-1)

  bf16x8 kreg, vreg;
  auto loadTile = [&](int t) {
    const long ro = base + ((long)t * 64 + r_) * 3072 + h * 64 + col_;
    kreg = *(const bf16x8*)(qkv + ro + 1024);
    vreg = *(const bf16x8*)(qkv + ro + 2048);
  };
  auto stageTile = [&](int bi) {
    __bf16* ks = &Ks[bi][0];
    __bf16* vt = &Vt[bi][0];
    // K row -> LDS (b128)
    *(bf16x8*)&ks[r_ * 72 + col_] = kreg;
    // V^T via pair-transpose + swizzle (b32 writes, 2-way banks = free)
    const int rr = (r_ & ~1) ^ sw;
    int vd[4], od[4];
    __builtin_memcpy(vd, &vreg, 16);
#pragma unroll
    for (int i = 0; i < 4; ++i) od[i] = __shfl_xor(vd[i], 8);
#pragma unroll
    for (int i = 0; i < 4; ++i) {
      const int j = jb + i;
      const int a = vd[j >> 1], bb = od[j >> 1];
      const int lo = oddr ? bb : a;
      const int hi = oddr ? a : bb;
      const int pair = (j & 1) ? (int)(((unsigned)lo >> 16) | (hi & 0xffff0000))
                               : (int)((lo & 0xffff) | (hi << 16));
      *(int*)&vt[(col_ + j) * 72 + rr] = pair;
    }
  };

  // prologue: stage tile 0 into buf0, issue loads for tile 1
  loadTile(0);
  stageTile(0);
  loadTile(1);  // Tb >= 18, always valid
  __syncthreads();

  for (int t = 0; t < Tb; ++t) {
    const int cur = t & 1;
    const int kv0 = t * 64;
    const bool active = (t < Tp);              // wave-uniform
    const bool actA = (kv0 <= q0A + wq + 15);  // wave-uniform

    // S^T = K * Q^T (K-frags shared across both q-groups) from Ks[cur]
    f32x4 st[2][4];
#pragma unroll
    for (int kt = 0; kt < 4; ++kt) {
      st[1][kt] = (f32x4){0.f, 0.f, 0.f, 0.f};
      st[0][kt] = (f32x4){0.f, 0.f, 0.f, 0.f};
    }
    if (active) {
      __builtin_amdgcn_s_setprio(1);
#pragma unroll
      for (int ks = 0; ks < 2; ++ks) {
        bf16x8 ak[4];
#pragma unroll
        for (int kt = 0; kt < 4; ++kt)
          ak[kt] = *(const bf16x8*)&Ks[cur][(kt * 16 + lr) * 72 + ks * 32 + quad * 8];
#pragma unroll
        for (int kt = 0; kt < 4; ++kt) st[1][kt] = MFMA16(ak[kt], b_q[1][ks], st[1][kt]);
        if (actA) {
#pragma unroll
          for (int kt = 0; kt < 4; ++kt) st[0][kt] = MFMA16(ak[kt], b_q[0][ks], st[0][kt]);
        }
      }
      __builtin_amdgcn_s_setprio(0);
    }

    // stage tile t+1 into the other buffer (overlaps with softmax below),
    // then issue global loads for tile t+2 (consumed by next iter's stage).
    if (t + 1 < Tb) stageTile(cur ^ 1);
    if (t + 2 < Tb) loadTile(t + 2);

    if (active) {
      // softmax for BOTH q-groups (independent chains -> ILP), P -> LDS
#pragma unroll
      for (int qg = 1; qg >= 0; --qg) {
        if (qg == 0 && !actA) continue;
        const int q0X = (qg == 0) ? q0A : q0B;
        // scale (exp2 domain) + causal mask
        if (kv0 + 64 <= q0X + wq) {
#pragma unroll
          for (int kt = 0; kt < 4; ++kt)
#pragma unroll
            for (int r = 0; r < 4; ++r) st[qg][kt][r] *= SC;
        } else {
#pragma unroll
          for (int kt = 0; kt < 4; ++kt) {
            const int d0 = kv0 + kt * 16 + quad * 4 - qi[qg];
#pragma unroll
            for (int r = 0; r < 4; ++r)
              st[qg][kt][r] = (d0 + r <= 0) ? st[qg][kt][r] * SC : NEGS;
          }
        }
        // online softmax (in-lane over 16 kv + 2 shfl)
        float mx = st[qg][0][0];
#pragma unroll
        for (int kt = 0; kt < 4; ++kt)
#pragma unroll
          for (int r = 0; r < 4; ++r) mx = fmaxf(mx, st[qg][kt][r]);
        mx = fmaxf(mx, __shfl_xor(mx, 16));
        mx = fmaxf(mx, __shfl_xor(mx, 32));
        // T13 defer-rescale: keep old max while growth <= 8 (P bounded by 2^8)
        const bool noresc = __all(mx - m_i[qg] <= 8.f);
        const float mnew = noresc ? m_i[qg] : fmaxf(m_i[qg], mx);
        float rs = 0.f;
#pragma unroll
        for (int kt = 0; kt < 4; ++kt)
#pragma unroll
          for (int r = 0; r < 4; ++r) {
            const float p = exp2f(st[qg][kt][r] - mnew);
            st[qg][kt][r] = p;
            rs += p;
          }
        rs += __shfl_xor(rs, 16);
        rs += __shfl_xor(rs, 32);
        // P -> wave-private LDS (b64 writes, 2-way = free)
#pragma unroll
        for (int kt = 0; kt < 4; ++kt) {
          bf16x4 pv;
#pragma unroll
          for (int r = 0; r < 4; ++r) pv[r] = (__bf16)st[qg][kt][r];
          *(bf16x4*)&pqw[(qg * 16 + lr) * 72 + kt * 16 + quad * 4] = pv;
        }
        if (noresc) {
          l_i[qg] += rs;
        } else {
          const float alpha = exp2f(m_i[qg] - mnew);
          l_i[qg] = l_i[qg] * alpha + rs;
          m_i[qg] = mnew;
#pragma unroll
          for (int dt = 0; dt < 4; ++dt)
#pragma unroll
            for (int r = 0; r < 4; ++r) o_acc[qg][dt][r] *= alpha;
        }
      }

      // single LDS-only fence: P writes visible to own wave's ds_reads;
      // leaves the depth-2 global prefetch in flight.
      asm volatile("s_waitcnt lgkmcnt(0)" ::: "memory");
      __builtin_amdgcn_sched_barrier(0);

      // O^T += V^T * P^T; av (V^T) fragments shared by both q-groups
      __builtin_amdgcn_s_setprio(1);
#pragma unroll
      for (int ks = 0; ks < 2; ++ks) {
        bf16x8 av[4];
#pragma unroll
        for (int dt = 0; dt < 4; ++dt) {
          const int blk = ((ks << 2) + quad) ^ ((2 * dt + (lr >> 3)) & 3);
          av[dt] = *(const bf16x8*)&Vt[cur][(dt * 16 + lr) * 72 + (blk << 3)];
        }
        {
          bf16x8 bp = *(const bf16x8*)&pqw[(16 + lr) * 72 + ks * 32 + quad * 8];
#pragma unroll
          for (int dt = 0; dt < 4; ++dt) o_acc[1][dt] = MFMA16(av[dt], bp, o_acc[1][dt]);
        }
        if (actA) {
          bf16x8 bp = *(const bf16x8*)&pqw[lr * 72 + ks * 32 + quad * 8];
#pragma unroll
          for (int dt = 0; dt < 4; ++dt) o_acc[0][dt] = MFMA16(av[dt], bp, o_acc[0][dt]);
        }
      }
      __builtin_amdgcn_s_setprio(0);
    }

    __syncthreads();  // single barrier per tile: staging of t+1 visible,
                      // reads of buf[cur] complete before iter t+1 overwrites
  }

  // epilogue: O/l -> q-slice in place
#pragma unroll
  for (int qg = 0; qg < 2; ++qg) {
    const float inv = 1.f / fmaxf(l_i[qg], 1e-30f);
    const long obase = base + (long)qi[qg] * 3072 + h * 64 + quad * 4;
#pragma unroll
    for (int dt = 0; dt < 4; ++dt) {
      bf16x4 ov;
#pragma unroll
      for (int r = 0; r < 4; ++r) ov[r] = (__bf16)(o_acc[qg][dt][r] * inv);
      *(bf16x4*)(qkv + obase + dt * 16) = ov;
    }
  }
}

extern "C" void kernel_launch(void* const* d_in, const int* in_sizes, int n_in,
                              void* d_out, int out_size, void* d_ws, size_t ws_size,
                              hipStream_t stream) {
  const float* x = (const float*)d_in[0];
  const float* w_qkv = (const float*)d_in[1];
  const float* w_o = (const float*)d_in[2];
  for (int i = 0; i < n_in; ++i) {
    if (in_sizes[i] == MTOT * DM) x = (const float*)d_in[i];
    else if (in_sizes[i] == 3 * DM * DM) w_qkv = (const float*)d_in[i];
    else if (in_sizes[i] == DM * DM) w_o = (const float*)d_in[i];
  }
  float* out = (float*)d_out;  // FP32 output per reference dtype

  const size_t qkvBytes = (size_t)MTOT * 3072 * 2;       // 24 MiB
  const size_t xbBytes = (size_t)MTOT * DM * 2;          // 8 MiB
  const size_t wqBytes = (size_t)3 * DM * DM * 2;        // 6 MiB
  const size_t woBytes = (size_t)DM * DM * 2;            // 2 MiB
  const size_t needFast = qkvBytes + xbBytes + wqBytes + woBytes;  // 40 MiB

  __bf16* qkv = (__bf16*)d_ws;

  if (ws_size >= needFast) {
    __bf16* xb = (__bf16*)((char*)d_ws + qkvBytes);
    __bf16* wqb = (__bf16*)((char*)d_ws + qkvBytes + xbBytes);
    __bf16* wob = (__bf16*)((char*)d_ws + qkvBytes + xbBytes + wqBytes);
    cvt_all<<<4096, 256, 0, stream>>>(x, w_qkv, w_o, xb, wqb, wob);
    gemm_bt<__bf16><<<dim3(3072 / 128, MTOT / 128), 256, 0, stream>>>(
        xb, wqb, qkv, MTOT, 3072, DM, DM, 1e4f);
    attn_fwd<<<dim3(8, NH, BATCH), 512, 0, stream>>>(qkv);
    gemm_bt64<float><<<dim3(DM / 128, MTOT / 64), 256, 0, stream>>>(
        qkv, wob, out, MTOT, DM, DM, 3072, 2e4f);
  } else if (ws_size >= qkvBytes) {
    gemm_nt<1, 1, __bf16><<<dim3(3072 / 128, MTOT / 128), 256, 0, stream>>>(
        x, w_qkv, qkv, MTOT, 3072, DM, DM, 1e4f);
    attn_fwd<<<dim3(8, NH, BATCH), 512, 0, stream>>>(qkv);
    gemm_nt<0, 1, float><<<dim3(DM / 128, MTOT / 128), 256, 0, stream>>>(
        qkv, w_o, out, MTOT, DM, DM, 3072, 2e4f);
  } else {
    sentinel_fill<<<256, 256, 0, stream>>>(out, out_size);
  }
}

// Round 8
// 206.328 us; speedup vs baseline: 1.0786x; 1.0618x over previous
//
#include <hip/hip_runtime.h>

constexpr int SEQ = 2048;
constexpr int DM = 1024;
constexpr int NH = 16;
constexpr int BATCH = 2;
constexpr int MTOT = BATCH * SEQ;   // 4096

typedef __bf16 bf16x8 __attribute__((ext_vector_type(8)));
typedef __bf16 bf16x4 __attribute__((ext_vector_type(4)));
typedef float f32x4 __attribute__((ext_vector_type(4)));

#define MFMA16(a, b, c) __builtin_amdgcn_mfma_f32_16x16x32_bf16((a), (b), (c), 0, 0, 0)

__device__ __forceinline__ void async_copy16(const void* g, void* l) {
  __builtin_amdgcn_global_load_lds((const __attribute__((address_space(1))) void*)g,
                                   (__attribute__((address_space(3))) void*)l, 16, 0, 0);
}

// T1 bijective XCD swizzle (kept from R7): contiguous block chunks per XCD.
__device__ __forceinline__ void xcd_swizzle(int& bx, int& by) {
  const int gx = gridDim.x;
  const int nwg = gx * gridDim.y;
  const int bid = blockIdx.y * gx + blockIdx.x;
  const int cpx = nwg >> 3;
  const int v = (bid & 7) * cpx + (bid >> 3);
  by = v / gx;
  bx = v - by * gx;
}

__global__ void sentinel_fill(float* out, int n) {
  int i = blockIdx.x * blockDim.x + threadIdx.x;
  for (; i < n; i += gridDim.x * blockDim.x) out[i] = 0.25f;
}

// one-shot fp32 -> bf16 conversion of x, w_qkv, w_o
__global__ __launch_bounds__(256) void cvt_all(const float* __restrict__ x,
                                               const float* __restrict__ wq,
                                               const float* __restrict__ wo,
                                               __bf16* __restrict__ xb,
                                               __bf16* __restrict__ wqb,
                                               __bf16* __restrict__ wob) {
  const long i = (long)(blockIdx.x * 256 + threadIdx.x) * 8;
  const float* src;
  __bf16* dst;
  long off;
  if (i < 4194304) { src = x; dst = xb; off = i; }
  else if (i < 7340032) { src = wq; dst = wqb; off = i - 4194304; }
  else { src = wo; dst = wob; off = i - 7340032; }
  f32x4 lo = *(const f32x4*)(src + off);
  f32x4 hi = *(const f32x4*)(src + off + 4);
  bf16x8 r;
#pragma unroll
  for (int j = 0; j < 4; ++j) { r[j] = (__bf16)lo[j]; r[4 + j] = (__bf16)hi[j]; }
  *(bf16x8*)(dst + off) = r;
}

// FAST GEMM: C[M,N]=A[M,K]*B[N,K]^T, 128x128 tile, m97 fragment geometry.
// R8: counted-vmcnt 3-buffer pipeline (T4). Per K-step:
//   vmcnt(4) [stage(t) retired, stage(t+1) IN FLIGHT] -> raw s_barrier
//   [global visibility + buf[(t-1)%3] reads complete] -> stage(t+2) into that
//   buf -> ds_read buf[t%3] + MFMA. No vmcnt(0) drain in the loop (the R6
//   2-buffer loop drained every step: ~300cyc stall x32). Final iter: vmcnt(0).
// Raw s_barrier, NOT __syncthreads (which force-drains vmcnt). LDS 48 KB.
template <typename OutT>
__global__ __launch_bounds__(256) void gemm_bt(const __bf16* __restrict__ A,
                                               const __bf16* __restrict__ B,
                                               OutT* __restrict__ C,
                                               int M, int N, int K, int lda,
                                               float nanSig) {
  __shared__ alignas(16) __bf16 As[3][128 * 32];
  __shared__ alignas(16) __bf16 Bs[3][128 * 32];
  const int tid = threadIdx.x;
  const int lane = tid & 63;
  const int wave = tid >> 6;
  const int lr = lane & 15;
  const int quad = lane >> 4;
  const int wm = (wave >> 1) * 64;
  const int wn = (wave & 1) * 64;
  int bx, by;
  xcd_swizzle(bx, by);
  const int m0 = by * 128;
  const int n0 = bx * 128;

  const int ra = tid >> 2;
  const int ca = (tid & 3) * 8;
  const __bf16* gA0 = A + (long)(m0 + ra) * lda + ca;
  const __bf16* gA1 = A + (long)(m0 + 64 + ra) * lda + ca;
  const __bf16* gB0 = B + (long)(n0 + ra) * K + ca;
  const __bf16* gB1 = B + (long)(n0 + 64 + ra) * K + ca;

  f32x4 acc[4][4];
#pragma unroll
  for (int i = 0; i < 4; ++i)
#pragma unroll
    for (int j = 0; j < 4; ++j) acc[i][j] = (f32x4){0.f, 0.f, 0.f, 0.f};

  auto stage = [&](int bi, int k0) {
    async_copy16(gA0 + k0, &As[bi][wave * 512]);
    async_copy16(gA1 + k0, &As[bi][2048 + wave * 512]);
    async_copy16(gB0 + k0, &Bs[bi][wave * 512]);
    async_copy16(gB1 + k0, &Bs[bi][2048 + wave * 512]);
  };

  const int nt = K >> 5;
  stage(0, 0);
  if (nt > 1) stage(1, 32);

  int cur = 0;
  for (int t = 0; t < nt; ++t) {
    // stage(t) must be retired before the barrier; stage(t+1) stays in flight.
    if (t + 1 < nt) {
      asm volatile("s_waitcnt vmcnt(4)" ::: "memory");
    } else {
      asm volatile("s_waitcnt vmcnt(0)" ::: "memory");
    }
    __builtin_amdgcn_sched_barrier(0);
    __builtin_amdgcn_s_barrier();  // stage(t) visible; buf[(t-1)%3] reads done
    if (t + 2 < nt) stage(cur == 0 ? 2 : cur - 1, (t + 2) * 32);  // (t+2)%3

    bf16x8 af[4], bfr[4];
#pragma unroll
    for (int i = 0; i < 4; ++i)
      af[i] = *(const bf16x8*)&As[cur][(wm + i * 16 + lr) * 32 + quad * 8];
#pragma unroll
    for (int j = 0; j < 4; ++j)
      bfr[j] = *(const bf16x8*)&Bs[cur][(wn + j * 16 + lr) * 32 + quad * 8];
    __builtin_amdgcn_s_setprio(1);
#pragma unroll
    for (int i = 0; i < 4; ++i)
#pragma unroll
      for (int j = 0; j < 4; ++j) acc[i][j] = MFMA16(af[i], bfr[j], acc[i][j]);
    __builtin_amdgcn_s_setprio(0);
    cur = (cur == 2) ? 0 : cur + 1;
  }

#pragma unroll
  for (int i = 0; i < 4; ++i) {
    const int row = m0 + wm + i * 16 + quad * 4;
#pragma unroll
    for (int j = 0; j < 4; ++j) {
      const int col = n0 + wn + j * 16 + lr;
#pragma unroll
      for (int r = 0; r < 4; ++r) {
        float v = acc[i][j][r];
        if (!(v == v)) v = nanSig;
        C[(long)(row + r) * N + col] = (OutT)v;
      }
    }
  }
}

// 64x128-tile variant for gemm2 (R7), with the same R8 counted-vmcnt 3-buffer
// pipeline. 3 loads per stage -> vmcnt(3) steady-state. LDS 36 KB.
template <typename OutT>
__global__ __launch_bounds__(256) void gemm_bt64(const __bf16* __restrict__ A,
                                                 const __bf16* __restrict__ B,
                                                 OutT* __restrict__ C,
                                                 int M, int N, int K, int lda,
                                                 float nanSig) {
  __shared__ alignas(16) __bf16 As[3][64 * 32];
  __shared__ alignas(16) __bf16 Bs[3][128 * 32];
  const int tid = threadIdx.x;
  const int lane = tid & 63;
  const int wave = tid >> 6;
  const int lr = lane & 15;
  const int quad = lane >> 4;
  const int wm = (wave >> 1) * 32;
  const int wn = (wave & 1) * 64;
  int bx, by;
  xcd_swizzle(bx, by);
  const int m0 = by * 64;
  const int n0 = bx * 128;

  const int ra = tid >> 2;          // 0..63
  const int ca = (tid & 3) * 8;
  const __bf16* gA0 = A + (long)(m0 + ra) * lda + ca;
  const __bf16* gB0 = B + (long)(n0 + ra) * K + ca;
  const __bf16* gB1 = B + (long)(n0 + 64 + ra) * K + ca;

  f32x4 acc[2][4];
#pragma unroll
  for (int i = 0; i < 2; ++i)
#pragma unroll
    for (int j = 0; j < 4; ++j) acc[i][j] = (f32x4){0.f, 0.f, 0.f, 0.f};

  auto stage = [&](int bi, int k0) {
    async_copy16(gA0 + k0, &As[bi][wave * 512]);
    async_copy16(gB0 + k0, &Bs[bi][wave * 512]);
    async_copy16(gB1 + k0, &Bs[bi][2048 + wave * 512]);
  };

  const int nt = K >> 5;
  stage(0, 0);
  if (nt > 1) stage(1, 32);

  int cur = 0;
  for (int t = 0; t < nt; ++t) {
    if (t + 1 < nt) {
      asm volatile("s_waitcnt vmcnt(3)" ::: "memory");
    } else {
      asm volatile("s_waitcnt vmcnt(0)" ::: "memory");
    }
    __builtin_amdgcn_sched_barrier(0);
    __builtin_amdgcn_s_barrier();
    if (t + 2 < nt) stage(cur == 0 ? 2 : cur - 1, (t + 2) * 32);

    bf16x8 af[2], bfr[4];
#pragma unroll
    for (int i = 0; i < 2; ++i)
      af[i] = *(const bf16x8*)&As[cur][(wm + i * 16 + lr) * 32 + quad * 8];
#pragma unroll
    for (int j = 0; j < 4; ++j)
      bfr[j] = *(const bf16x8*)&Bs[cur][(wn + j * 16 + lr) * 32 + quad * 8];
    __builtin_amdgcn_s_setprio(1);
#pragma unroll
    for (int i = 0; i < 2; ++i)
#pragma unroll
      for (int j = 0; j < 4; ++j) acc[i][j] = MFMA16(af[i], bfr[j], acc[i][j]);
    __builtin_amdgcn_s_setprio(0);
    cur = (cur == 2) ? 0 : cur + 1;
  }

#pragma unroll
  for (int i = 0; i < 2; ++i) {
    const int row = m0 + wm + i * 16 + quad * 4;
#pragma unroll
    for (int j = 0; j < 4; ++j) {
      const int col = n0 + wn + j * 16 + lr;
#pragma unroll
      for (int r = 0; r < 4; ++r) {
        float v = acc[i][j][r];
        if (!(v == v)) v = nanSig;
        C[(long)(row + r) * N + col] = (OutT)v;
      }
    }
  }
}

// SLOW fallback GEMM (inline fp32 cvt, verified R9).
template <int F32>
__device__ __forceinline__ bf16x8 load_cvt8(const void* base, long off) {
  if constexpr (F32) {
    const float* p = (const float*)base + off;
    f32x4 lo = *(const f32x4*)p;
    f32x4 hi = *(const f32x4*)(p + 4);
    bf16x8 r;
#pragma unroll
    for (int j = 0; j < 4; ++j) { r[j] = (__bf16)lo[j]; r[4 + j] = (__bf16)hi[j]; }
    return r;
  } else {
    return *(const bf16x8*)((const __bf16*)base + off);
  }
}

template <int AF32, int BF32, typename OutT>
__global__ __launch_bounds__(256) void gemm_nt(const void* __restrict__ Av,
                                               const void* __restrict__ Bv,
                                               OutT* __restrict__ C,
                                               int M, int N, int K, int lda,
                                               float nanSig) {
  __shared__ alignas(16) __bf16 As[128 * 32];
  __shared__ alignas(16) __bf16 Bs[128 * 32];
  const int tid = threadIdx.x;
  const int lane = tid & 63;
  const int wave = tid >> 6;
  const int lr = lane & 15;
  const int quad = lane >> 4;
  const int wm = (wave >> 1) * 64;
  const int wn = (wave & 1) * 64;
  const int m0 = blockIdx.y * 128;
  const int n0 = blockIdx.x * 128;

  const int r0 = tid >> 2;
  const int r1 = 64 + (tid >> 2);
  const int cc = (tid & 3) * 8;
  const long aBase0 = (long)(m0 + r0) * lda + cc;
  const long aBase1 = (long)(m0 + r1) * lda + cc;
  const long bBase0 = (long)(n0 + r0) * K + cc;
  const long bBase1 = (long)(n0 + r1) * K + cc;
  __bf16* lA0 = &As[r0 * 32 + cc];
  __bf16* lA1 = &As[r1 * 32 + cc];
  __bf16* lB0 = &Bs[r0 * 32 + cc];
  __bf16* lB1 = &Bs[r1 * 32 + cc];

  f32x4 acc[4][4];
#pragma unroll
  for (int i = 0; i < 4; ++i)
#pragma unroll
    for (int j = 0; j < 4; ++j) acc[i][j] = (f32x4){0.f, 0.f, 0.f, 0.f};

  for (int k0 = 0; k0 < K; k0 += 32) {
    bf16x8 va0 = load_cvt8<AF32>(Av, aBase0 + k0);
    bf16x8 va1 = load_cvt8<AF32>(Av, aBase1 + k0);
    bf16x8 vb0 = load_cvt8<BF32>(Bv, bBase0 + k0);
    bf16x8 vb1 = load_cvt8<BF32>(Bv, bBase1 + k0);
    __syncthreads();
    *(bf16x8*)lA0 = va0;
    *(bf16x8*)lA1 = va1;
    *(bf16x8*)lB0 = vb0;
    *(bf16x8*)lB1 = vb1;
    __syncthreads();
    bf16x8 af[4], bfr[4];
#pragma unroll
    for (int i = 0; i < 4; ++i) af[i] = *(const bf16x8*)&As[(wm + i * 16 + lr) * 32 + quad * 8];
#pragma unroll
    for (int j = 0; j < 4; ++j) bfr[j] = *(const bf16x8*)&Bs[(wn + j * 16 + lr) * 32 + quad * 8];
#pragma unroll
    for (int i = 0; i < 4; ++i)
#pragma unroll
      for (int j = 0; j < 4; ++j) acc[i][j] = MFMA16(af[i], bfr[j], acc[i][j]);
  }

#pragma unroll
  for (int i = 0; i < 4; ++i) {
    const int row = m0 + wm + i * 16 + quad * 4;
#pragma unroll
    for (int j = 0; j < 4; ++j) {
      const int col = n0 + wn + j * 16 + lr;
#pragma unroll
      for (int r = 0; r < 4; ++r) {
        float v = acc[i][j][r];
        if (!(v == v)) v = nanSig;
        C[(long)(row + r) * N + col] = (OutT)v;
      }
    }
  }
}

// Flash causal attention, S^T form. R5 FAT BLOCKS (kept, untouched): 512
// threads = 8 waves, block owns pairs (2j, 2j+1). Grid 8x16x2 = 256 blocks.
// LDS dbuf Ks/Vt, single barrier per tile, shared-av PV, T13 defer-rescale,
// T5 setprio, LDS-only P fence. ~90us steady (79-91 noise band).
// Vt is XOR-swizzled (kv ^= 8*((d>>3)&3)) to kill the 8-way write conflict.
__global__ __launch_bounds__(512, 2) void attn_fwd(__bf16* __restrict__ qkv) {
  const int jj = blockIdx.x;      // 0..7: pair group
  const int h = blockIdx.y;
  const int b = blockIdx.z;
  const int tid = threadIdx.x;
  const int lane = tid & 63;
  const int wave = tid >> 6;      // 0..7
  const int ps = wave >> 2;       // 0: pair 2j, 1: pair 2j+1
  const int pi = 2 * jj + ps;     // 0..15
  const int q0A = pi * 64;
  const int q0B = (31 - pi) * 64;
  const int lr = lane & 15;
  const int quad = lane >> 4;
  const int wq = (wave & 3) * 16;

  __shared__ alignas(16) __bf16 Ks[2][64 * 72];  // K rows [kv][d], double-buffered
  __shared__ alignas(16) __bf16 Vt[2][64 * 72];  // V^T [d][kv^swz], double-buffered
  __shared__ alignas(16) __bf16 Pq[256 * 72];    // P [wave*32 + qg*16 + q][kv]

  __bf16* pqw = &Pq[wave * 32 * 72];
  const long base = (long)b * SEQ * 3072;
  const int qi[2] = {q0A + wq + lr, q0B + wq + lr};

  // Q as B-operand fragments (loaded once)
  bf16x8 b_q[2][2];
#pragma unroll
  for (int qg = 0; qg < 2; ++qg) {
    const long rowoff = base + (long)qi[qg] * 3072 + h * 64;
    b_q[qg][0] = *(const bf16x8*)(qkv + rowoff + quad * 8);
    b_q[qg][1] = *(const bf16x8*)(qkv + rowoff + 32 + quad * 8);
  }

  const float NEGS = -30000.f;
  const float SC = 0.18033688f;  // 0.125 * log2(e): softmax in exp2 domain
  float m_i[2] = {NEGS, NEGS}, l_i[2] = {0.f, 0.f};
  f32x4 o_acc[2][4];
#pragma unroll
  for (int qg = 0; qg < 2; ++qg)
#pragma unroll
    for (int dt = 0; dt < 4; ++dt) o_acc[qg][dt] = (f32x4){0.f, 0.f, 0.f, 0.f};

  // staging thread geometry (512 stagers: 1 row each)
  const int r_ = tid >> 3;            // 0..63
  const int col_ = (tid & 7) * 8;     // 0..56
  const int l8 = tid & 7;
  const int sw = (l8 & 3) << 3;       // Vt swizzle amount for this thread's cols
  const bool oddr = (tid >> 3) & 1;
  const int jb = oddr ? 4 : 0;

  const int Tb = 32 - 2 * jj;         // staged tiles (pair 2j's range), >= 18
  const int Tp = 32 - pi;             // this wave's pair compute range (Tb or Tb-1)

  bf16x8 kreg, vreg;
  auto loadTile = [&](int t) {
    const long ro = base + ((long)t * 64 + r_) * 3072 + h * 64 + col_;
    kreg = *(const bf16x8*)(qkv + ro + 1024);
    vreg = *(const bf16x8*)(qkv + ro + 2048);
  };
  auto stageTile = [&](int bi) {
    __bf16* ks = &Ks[bi][0];
    __bf16* vt = &Vt[bi][0];
    // K row -> LDS (b128)
    *(bf16x8*)&ks[r_ * 72 + col_] = kreg;
    // V^T via pair-transpose + swizzle (b32 writes, 2-way banks = free)
    const int rr = (r_ & ~1) ^ sw;
    int vd[4], od[4];
    __builtin_memcpy(vd, &vreg, 16);
#pragma unroll
    for (int i = 0; i < 4; ++i) od[i] = __shfl_xor(vd[i], 8);
#pragma unroll
    for (int i = 0; i < 4; ++i) {
      const int j = jb + i;
      const int a = vd[j >> 1], bb = od[j >> 1];
      const int lo = oddr ? bb : a;
      const int hi = oddr ? a : bb;
      const int pair = (j & 1) ? (int)(((unsigned)lo >> 16) | (hi & 0xffff0000))
                               : (int)((lo & 0xffff) | (hi << 16));
      *(int*)&vt[(col_ + j) * 72 + rr] = pair;
    }
  };

  // prologue: stage tile 0 into buf0, issue loads for tile 1
  loadTile(0);
  stageTile(0);
  loadTile(1);  // Tb >= 18, always valid
  __syncthreads();

  for (int t = 0; t < Tb; ++t) {
    const int cur = t & 1;
    const int kv0 = t * 64;
    const bool active = (t < Tp);              // wave-uniform
    const bool actA = (kv0 <= q0A + wq + 15);  // wave-uniform

    // S^T = K * Q^T (K-frags shared across both q-groups) from Ks[cur]
    f32x4 st[2][4];
#pragma unroll
    for (int kt = 0; kt < 4; ++kt) {
      st[1][kt] = (f32x4){0.f, 0.f, 0.f, 0.f};
      st[0][kt] = (f32x4){0.f, 0.f, 0.f, 0.f};
    }
    if (active) {
      __builtin_amdgcn_s_setprio(1);
#pragma unroll
      for (int ks = 0; ks < 2; ++ks) {
        bf16x8 ak[4];
#pragma unroll
        for (int kt = 0; kt < 4; ++kt)
          ak[kt] = *(const bf16x8*)&Ks[cur][(kt * 16 + lr) * 72 + ks * 32 + quad * 8];
#pragma unroll
        for (int kt = 0; kt < 4; ++kt) st[1][kt] = MFMA16(ak[kt], b_q[1][ks], st[1][kt]);
        if (actA) {
#pragma unroll
          for (int kt = 0; kt < 4; ++kt) st[0][kt] = MFMA16(ak[kt], b_q[0][ks], st[0][kt]);
        }
      }
      __builtin_amdgcn_s_setprio(0);
    }

    // stage tile t+1 into the other buffer (overlaps with softmax below),
    // then issue global loads for tile t+2 (consumed by next iter's stage).
    if (t + 1 < Tb) stageTile(cur ^ 1);
    if (t + 2 < Tb) loadTile(t + 2);

    if (active) {
      // softmax for BOTH q-groups (independent chains -> ILP), P -> LDS
#pragma unroll
      for (int qg = 1; qg >= 0; --qg) {
        if (qg == 0 && !actA) continue;
        const int q0X = (qg == 0) ? q0A : q0B;
        // scale (exp2 domain) + causal mask
        if (kv0 + 64 <= q0X + wq) {
#pragma unroll
          for (int kt = 0; kt < 4; ++kt)
#pragma unroll
            for (int r = 0; r < 4; ++r) st[qg][kt][r] *= SC;
        } else {
#pragma unroll
          for (int kt = 0; kt < 4; ++kt) {
            const int d0 = kv0 + kt * 16 + quad * 4 - qi[qg];
#pragma unroll
            for (int r = 0; r < 4; ++r)
              st[qg][kt][r] = (d0 + r <= 0) ? st[qg][kt][r] * SC : NEGS;
          }
        }
        // online softmax (in-lane over 16 kv + 2 shfl)
        float mx = st[qg][0][0];
#pragma unroll
        for (int kt = 0; kt < 4; ++kt)
#pragma unroll
          for (int r = 0; r < 4; ++r) mx = fmaxf(mx, st[qg][kt][r]);
        mx = fmaxf(mx, __shfl_xor(mx, 16));
        mx = fmaxf(mx, __shfl_xor(mx, 32));
        // T13 defer-rescale: keep old max while growth <= 8 (P bounded by 2^8)
        const bool noresc = __all(mx - m_i[qg] <= 8.f);
        const float mnew = noresc ? m_i[qg] : fmaxf(m_i[qg], mx);
        float rs = 0.f;
#pragma unroll
        for (int kt = 0; kt < 4; ++kt)
#pragma unroll
          for (int r = 0; r < 4; ++r) {
            const float p = exp2f(st[qg][kt][r] - mnew);
            st[qg][kt][r] = p;
            rs += p;
          }
        rs += __shfl_xor(rs, 16);
        rs += __shfl_xor(rs, 32);
        // P -> wave-private LDS (b64 writes, 2-way = free)
#pragma unroll
        for (int kt = 0; kt < 4; ++kt) {
          bf16x4 pv;
#pragma unroll
          for (int r = 0; r < 4; ++r) pv[r] = (__bf16)st[qg][kt][r];
          *(bf16x4*)&pqw[(qg * 16 + lr) * 72 + kt * 16 + quad * 4] = pv;
        }
        if (noresc) {
          l_i[qg] += rs;
        } else {
          const float alpha = exp2f(m_i[qg] - mnew);
          l_i[qg] = l_i[qg] * alpha + rs;
          m_i[qg] = mnew;
#pragma unroll
          for (int dt = 0; dt < 4; ++dt)
#pragma unroll
            for (int r = 0; r < 4; ++r) o_acc[qg][dt][r] *= alpha;
        }
      }

      // single LDS-only fence: P writes visible to own wave's ds_reads;
      // leaves the depth-2 global prefetch in flight.
      asm volatile("s_waitcnt lgkmcnt(0)" ::: "memory");
      __builtin_amdgcn_sched_barrier(0);

      // O^T += V^T * P^T; av (V^T) fragments shared by both q-groups
      __builtin_amdgcn_s_setprio(1);
#pragma unroll
      for (int ks = 0; ks < 2; ++ks) {
        bf16x8 av[4];
#pragma unroll
        for (int dt = 0; dt < 4; ++dt) {
          const int blk = ((ks << 2) + quad) ^ ((2 * dt + (lr >> 3)) & 3);
          av[dt] = *(const bf16x8*)&Vt[cur][(dt * 16 + lr) * 72 + (blk << 3)];
        }
        {
          bf16x8 bp = *(const bf16x8*)&pqw[(16 + lr) * 72 + ks * 32 + quad * 8];
#pragma unroll
          for (int dt = 0; dt < 4; ++dt) o_acc[1][dt] = MFMA16(av[dt], bp, o_acc[1][dt]);
        }
        if (actA) {
          bf16x8 bp = *(const bf16x8*)&pqw[lr * 72 + ks * 32 + quad * 8];
#pragma unroll
          for (int dt = 0; dt < 4; ++dt) o_acc[0][dt] = MFMA16(av[dt], bp, o_acc[0][dt]);
        }
      }
      __builtin_amdgcn_s_setprio(0);
    }

    __syncthreads();  // single barrier per tile: staging of t+1 visible,
                      // reads of buf[cur] complete before iter t+1 overwrites
  }

  // epilogue: O/l -> q-slice in place
#pragma unroll
  for (int qg = 0; qg < 2; ++qg) {
    const float inv = 1.f / fmaxf(l_i[qg], 1e-30f);
    const long obase = base + (long)qi[qg] * 3072 + h * 64 + quad * 4;
#pragma unroll
    for (int dt = 0; dt < 4; ++dt) {
      bf16x4 ov;
#pragma unroll
      for (int r = 0; r < 4; ++r) ov[r] = (__bf16)(o_acc[qg][dt][r] * inv);
      *(bf16x4*)(qkv + obase + dt * 16) = ov;
    }
  }
}

extern "C" void kernel_launch(void* const* d_in, const int* in_sizes, int n_in,
                              void* d_out, int out_size, void* d_ws, size_t ws_size,
                              hipStream_t stream) {
  const float* x = (const float*)d_in[0];
  const float* w_qkv = (const float*)d_in[1];
  const float* w_o = (const float*)d_in[2];
  for (int i = 0; i < n_in; ++i) {
    if (in_sizes[i] == MTOT * DM) x = (const float*)d_in[i];
    else if (in_sizes[i] == 3 * DM * DM) w_qkv = (const float*)d_in[i];
    else if (in_sizes[i] == DM * DM) w_o = (const float*)d_in[i];
  }
  float* out = (float*)d_out;  // FP32 output per reference dtype

  const size_t qkvBytes = (size_t)MTOT * 3072 * 2;       // 24 MiB
  const size_t xbBytes = (size_t)MTOT * DM * 2;          // 8 MiB
  const size_t wqBytes = (size_t)3 * DM * DM * 2;        // 6 MiB
  const size_t woBytes = (size_t)DM * DM * 2;            // 2 MiB
  const size_t needFast = qkvBytes + xbBytes + wqBytes + woBytes;  // 40 MiB

  __bf16* qkv = (__bf16*)d_ws;

  if (ws_size >= needFast) {
    __bf16* xb = (__bf16*)((char*)d_ws + qkvBytes);
    __bf16* wqb = (__bf16*)((char*)d_ws + qkvBytes + xbBytes);
    __bf16* wob = (__bf16*)((char*)d_ws + qkvBytes + xbBytes + wqBytes);
    cvt_all<<<4096, 256, 0, stream>>>(x, w_qkv, w_o, xb, wqb, wob);
    gemm_bt<__bf16><<<dim3(3072 / 128, MTOT / 128), 256, 0, stream>>>(
        xb, wqb, qkv, MTOT, 3072, DM, DM, 1e4f);
    attn_fwd<<<dim3(8, NH, BATCH), 512, 0, stream>>>(qkv);
    gemm_bt64<float><<<dim3(DM / 128, MTOT / 64), 256, 0, stream>>>(
        qkv, wob, out, MTOT, DM, DM, 3072, 2e4f);
  } else if (ws_size >= qkvBytes) {
    gemm_nt<1, 1, __bf16><<<dim3(3072 / 128, MTOT / 128), 256, 0, stream>>>(
        x, w_qkv, qkv, MTOT, 3072, DM, DM, 1e4f);
    attn_fwd<<<dim3(8, NH, BATCH), 512, 0, stream>>>(qkv);
    gemm_nt<0, 1, float><<<dim3(DM / 128, MTOT / 128), 256, 0, stream>>>(
        qkv, w_o, out, MTOT, DM, DM, 3072, 2e4f);
  } else {
    sentinel_fill<<<256, 256, 0, stream>>>(out, out_size);
  }
}